// Round 2
// baseline (221.382 us; speedup 1.0000x reference)
//
#include <hip/hip_runtime.h>

// out[b,h,w,c] = t1*w0[c] + t2*w1[c] + t3*w2[c]
// N = 67,108,864 fp32; memory-bound streaming. Ideal traffic 1.073 GB.
// Round-1: 219 us (4.9 TB/s effective). FETCH showed L3 absorbing ~half the
// input reads across replays; WRITE exactly ideal. This round: nontemporal
// stores (output is never re-read -> keep it out of L2/L3 so inputs stay
// resident) + 2x unrolled grid-stride (6 loads in flight / iter).

typedef float f32x4 __attribute__((ext_vector_type(4)));

__global__ __launch_bounds__(256) void merge3_kernel(
    const f32x4* __restrict__ t1,
    const f32x4* __restrict__ t2,
    const f32x4* __restrict__ t3,
    const float* __restrict__ weights,   // (C=256, 3) row-major
    f32x4* __restrict__ out,
    int n4)
{
    const int tid    = blockIdx.x * blockDim.x + threadIdx.x;
    const int stride = gridDim.x * blockDim.x;   // multiple of 256 -> mult of 64

    // Channel quad fixed across grid-stride iterations (stride % 64 == 0):
    const int cbase = (tid & 63) * 4;
    float w0[4], w1[4], w2[4];
    #pragma unroll
    for (int k = 0; k < 4; ++k) {
        w0[k] = weights[(cbase + k) * 3 + 0];
        w1[k] = weights[(cbase + k) * 3 + 1];
        w2[k] = weights[(cbase + k) * 3 + 2];
    }

    // n4 = 16,777,216; stride = 524,288 -> exactly 32 iterations, unroll x2.
    for (int i = tid; i < n4; i += 2 * stride) {
        const int j = i + stride;

        f32x4 a0 = t1[i], b0 = t2[i], c0 = t3[i];
        f32x4 a1 = t1[j], b1 = t2[j], c1 = t3[j];

        f32x4 o0, o1;
        #pragma unroll
        for (int k = 0; k < 4; ++k) {
            o0[k] = fmaf(a0[k], w0[k], fmaf(b0[k], w1[k], c0[k] * w2[k]));
            o1[k] = fmaf(a1[k], w0[k], fmaf(b1[k], w1[k], c1[k] * w2[k]));
        }

        __builtin_nontemporal_store(o0, &out[i]);
        __builtin_nontemporal_store(o1, &out[j]);
    }
}

extern "C" void kernel_launch(void* const* d_in, const int* in_sizes, int n_in,
                              void* d_out, int out_size, void* d_ws, size_t ws_size,
                              hipStream_t stream) {
    const f32x4* t1 = (const f32x4*)d_in[0];
    const f32x4* t2 = (const f32x4*)d_in[1];
    const f32x4* t3 = (const f32x4*)d_in[2];
    const float* w  = (const float*)d_in[3];
    f32x4* out = (f32x4*)d_out;

    const int n4 = out_size / 4;   // 16,777,216

    // 2048 blocks x 256 threads = 8192 waves = full chip wave capacity
    // (256 CU x 32 waves/CU); each thread does 16 unrolled-x2 iterations.
    dim3 grid(2048), block(256);
    merge3_kernel<<<grid, block, 0, stream>>>(t1, t2, t3, w, out, n4);
}